// Round 1
// baseline (423.470 us; speedup 1.0000x reference)
//
#include <hip/hip_runtime.h>
#include <cstdint>
#include <cstddef>

#define B 4
#define N 16
#define V 32
#define HW 25600
#define TOPK 7
#define PCH 10
#define CHUNK (HW / PCH)   // 2560
#define PIX 5              // pixels per register-blocked iteration

__device__ __forceinline__ bool better(float av, int ai, float bv, int bi) {
    return (av > bv) || (av == bv && ai < bi);
}

// ---------------- phase 1: per-(b,n) stats + top-7 ----------------
__global__ __launch_bounds__(256) void phase1(
    const float* __restrict__ pred, const float* __restrict__ feat,
    const float* __restrict__ gt, const int* __restrict__ valid,
    float* __restrict__ mean_emb, float* __restrict__ cntbuf,
    int* __restrict__ topidx, float* __restrict__ out) {
    int bn = blockIdx.x;
    int b = bn / N;
    const float* gtrow = gt + (size_t)bn * HW;
    const float* fb = feat + (size_t)b * V * HW;
    const float* pr = pred + (size_t)b * HW;
    int tid = threadIdx.x;

    __shared__ float lms[4][V];
    __shared__ float lcs[4][2];
    __shared__ float cv[256 * TOPK];
    __shared__ int   ci[256 * TOPK];
    __shared__ float rwv[4];
    __shared__ int   rwi[4], rws[4];

    float ms[V];
#pragma unroll
    for (int v = 0; v < V; ++v) ms[v] = 0.f;
    float cnt = 0.f, s2 = 0.f;
    float tv[TOPK]; int ti[TOPK];
#pragma unroll
    for (int j = 0; j < TOPK; ++j) { tv[j] = -INFINITY; ti[j] = 0x7fffffff; }

    for (int p = tid; p < HW; p += 256) {
        float g = gtrow[p];
        float c = pr[p] * g;
        if (better(c, p, tv[TOPK - 1], ti[TOPK - 1])) {
            tv[TOPK - 1] = c; ti[TOPK - 1] = p;
#pragma unroll
            for (int j = TOPK - 2; j >= 0; --j) {
                if (better(tv[j + 1], ti[j + 1], tv[j], ti[j])) {
                    float fv = tv[j]; int fi = ti[j];
                    tv[j] = tv[j + 1]; ti[j] = ti[j + 1];
                    tv[j + 1] = fv; ti[j + 1] = fi;
                }
            }
        }
        cnt += g;
        float fs = 0.f;
#pragma unroll
        for (int v = 0; v < V; ++v) {
            float f = fb[(size_t)v * HW + p];
            ms[v] = fmaf(g, f, ms[v]);
            fs = fmaf(f, f, fs);
        }
        s2 = fmaf(g, fs, s2);
    }

    int lane = tid & 63, wave = tid >> 6;
#pragma unroll
    for (int off = 32; off > 0; off >>= 1) {
        cnt += __shfl_down(cnt, off);
        s2  += __shfl_down(s2, off);
#pragma unroll
        for (int v = 0; v < V; ++v) ms[v] += __shfl_down(ms[v], off);
    }
    if (lane == 0) {
#pragma unroll
        for (int v = 0; v < V; ++v) lms[wave][v] = ms[v];
        lcs[wave][0] = cnt; lcs[wave][1] = s2;
    }
    // stash top-7 candidates
#pragma unroll
    for (int j = 0; j < TOPK; ++j) { cv[j * 256 + tid] = tv[j]; ci[j * 256 + tid] = ti[j]; }
    __syncthreads();

    if (tid == 0) {
        float c = lcs[0][0] + lcs[1][0] + lcs[2][0] + lcs[3][0];
        float S2 = lcs[0][1] + lcs[1][1] + lcs[2][1] + lcs[3][1];
        float pix = fmaxf(c, 1.0f);
        float musq = 0.f;
        for (int v = 0; v < V; ++v) {
            float mu = (lms[0][v] + lms[1][v] + lms[2][v] + lms[3][v]) / pix;
            mean_emb[bn * V + v] = mu;
            musq = fmaf(mu, mu, musq);
        }
        cntbuf[bn] = c;
        float emb = S2 / pix - musq;   // exact collapse of the l2 term; 0 when cnt==0
        float vw = (float)valid[bn];
        atomicAdd(out + 2, emb * vw);
    }

    // 7 rounds of block-wide argmax with (val desc, idx asc) tie-break
    for (int round = 0; round < TOPK; ++round) {
        float bv = -INFINITY; int bi = 0x7fffffff; int bs = -1;
#pragma unroll
        for (int j = 0; j < TOPK; ++j) {
            int slot = j * 256 + tid;
            float vv = cv[slot]; int ix = ci[slot];
            if (better(vv, ix, bv, bi)) { bv = vv; bi = ix; bs = slot; }
        }
#pragma unroll
        for (int off = 32; off > 0; off >>= 1) {
            float v2 = __shfl_down(bv, off);
            int i2 = __shfl_down(bi, off);
            int s2_ = __shfl_down(bs, off);
            if (better(v2, i2, bv, bi)) { bv = v2; bi = i2; bs = s2_; }
        }
        if (lane == 0) { rwv[wave] = bv; rwi[wave] = bi; rws[wave] = bs; }
        __syncthreads();
        if (tid == 0) {
            float fv = rwv[0]; int fi = rwi[0], fs = rws[0];
            for (int w = 1; w < 4; ++w)
                if (better(rwv[w], rwi[w], fv, fi)) { fv = rwv[w]; fi = rwi[w]; fs = rws[w]; }
            topidx[bn * TOPK + round] = fi;
            cv[fs] = -INFINITY; ci[fs] = 0x7fffffff;
        }
        __syncthreads();
    }
}

// ---------------- phase 2: 8-row sigmoid-GEMM dice sums ----------------
__global__ __launch_bounds__(256) void phase2(
    const float* __restrict__ feat, const float* __restrict__ gt,
    const float* __restrict__ mean_emb, const int* __restrict__ topidx,
    float* __restrict__ sums) {
    int blk = blockIdx.x;
    int pc = blk % PCH;
    int bn = blk / PCH;
    int b = bn / N;
    int tid = threadIdx.x;

    __shared__ float e[8][V];
    {
        int r = tid >> 5, v = tid & 31;
        float val;
        if (r == 0) val = mean_emb[bn * V + v];
        else {
            int ix = topidx[bn * TOPK + r - 1];
            val = feat[((size_t)b * V + v) * HW + ix];
        }
        e[r][v] = val;
    }
    __syncthreads();

    const float* fb = feat + (size_t)b * V * HW;
    const float* gtrow = gt + (size_t)bn * HW;
    float p2[8], tp[8];
#pragma unroll
    for (int r = 0; r < 8; ++r) { p2[r] = 0.f; tp[r] = 0.f; }

    int p0 = pc * CHUNK;
    for (int it = 0; it < 2; ++it) {
        int pbase = p0 + it * (PIX * 256) + tid;
        float g[PIX];
#pragma unroll
        for (int j = 0; j < PIX; ++j) g[j] = gtrow[pbase + j * 256];
        float m[PIX][8];
#pragma unroll
        for (int j = 0; j < PIX; ++j)
#pragma unroll
            for (int r = 0; r < 8; ++r) m[j][r] = 0.f;

#pragma unroll
        for (int q = 0; q < 8; ++q) {           // v in quads of 4
            float eqf[8][4];
#pragma unroll
            for (int r = 0; r < 8; ++r) {
                float4 t = *reinterpret_cast<const float4*>(&e[r][q * 4]);
                eqf[r][0] = t.x; eqf[r][1] = t.y; eqf[r][2] = t.z; eqf[r][3] = t.w;
            }
#pragma unroll
            for (int vv = 0; vv < 4; ++vv) {
                const float* fp = fb + (size_t)(q * 4 + vv) * HW;
#pragma unroll
                for (int j = 0; j < PIX; ++j) {
                    float f = fp[pbase + j * 256];
#pragma unroll
                    for (int r = 0; r < 8; ++r) m[j][r] = fmaf(eqf[r][vv], f, m[j][r]);
                }
            }
        }
#pragma unroll
        for (int j = 0; j < PIX; ++j) {
#pragma unroll
            for (int r = 0; r < 8; ++r) {
                float s = 1.f / (1.f + __expf(-m[j][r]));
                p2[r] = fmaf(s, s, p2[r]);
                tp[r] = fmaf(g[j], s, tp[r]);
            }
        }
    }

    int lane = tid & 63, wave = tid >> 6;
#pragma unroll
    for (int off = 32; off > 0; off >>= 1) {
#pragma unroll
        for (int r = 0; r < 8; ++r) {
            p2[r] += __shfl_down(p2[r], off);
            tp[r] += __shfl_down(tp[r], off);
        }
    }
    __shared__ float red[4][16];
    if (lane == 0) {
#pragma unroll
        for (int r = 0; r < 8; ++r) { red[wave][r * 2] = p2[r]; red[wave][r * 2 + 1] = tp[r]; }
    }
    __syncthreads();
    if (tid < 16) {
        float s = red[0][tid] + red[1][tid] + red[2][tid] + red[3][tid];
        atomicAdd(sums + bn * 16 + tid, s);
    }
}

// ---------------- phase 3: fold dice sums into losses ----------------
__global__ void phase3(const float* __restrict__ sums, const float* __restrict__ cntbuf,
                       const int* __restrict__ valid, float* __restrict__ out) {
    int bn = threadIdx.x;   // 64 threads
    float vw = (float)valid[bn];
    float cnt = cntbuf[bn];
    float mloss = 0.f, iloss = 0.f;
#pragma unroll
    for (int r = 0; r < 8; ++r) {
        float p2 = sums[bn * 16 + r * 2];
        float tp = sums[bn * 16 + r * 2 + 1];
        float denom = fmaxf(p2 + cnt, 1e-8f);
        float dice = 1.f - 2.f * tp / denom;
        if (r == 0) mloss = dice * vw;
        else iloss += dice * vw;
    }
    atomicAdd(out + 0, mloss);
    atomicAdd(out + 1, iloss);
}

extern "C" void kernel_launch(void* const* d_in, const int* in_sizes, int n_in,
                              void* d_out, int out_size, void* d_ws, size_t ws_size,
                              hipStream_t stream) {
    const float* pred = (const float*)d_in[0];
    const float* feat = (const float*)d_in[1];
    const float* gtin = (const float*)d_in[2];
    const int* valid  = (const int*)d_in[3];
    float* out = (float*)d_out;

    char* ws = (char*)d_ws;
    float* mean_emb = (float*)ws;                  // 64*32 f = 8192 B
    float* cntbuf   = (float*)(ws + 8192);         // 64 f
    float* sums     = (float*)(ws + 8448);         // 64*16 f = 4096 B
    int*   topidx   = (int*)(ws + 12544);          // 64*7 i

    hipMemsetAsync(out, 0, 3 * sizeof(float), stream);
    hipMemsetAsync(sums, 0, 64 * 16 * sizeof(float), stream);

    phase1<<<B * N, 256, 0, stream>>>(pred, feat, gtin, valid, mean_emb, cntbuf, topidx, out);
    phase2<<<B * N * PCH, 256, 0, stream>>>(feat, gtin, mean_emb, topidx, sums);
    phase3<<<1, 64, 0, stream>>>(sums, cntbuf, valid, out);
}

// Round 2
// 115.692 us; speedup vs baseline: 3.6603x; 3.6603x over previous
//
#include <hip/hip_runtime.h>
#include <cstdint>
#include <cstddef>

#define B 4
#define N 16
#define V 32
#define HW 25600
#define TOPK 7
#define NC 25          // pixel chunks per (b,n)
#define CHUNK 1024     // 256 threads * 4 px

__device__ __forceinline__ bool better(float av, int ai, float bv, int bi) {
    return (av > bv) || (av == bv && ai < bi);
}

// ---------------- kernel A: per-(b,n,chunk) stats + top-7 candidates ----------------
__global__ __launch_bounds__(256) void kstats(
    const float* __restrict__ pred, const float* __restrict__ feat,
    const float* __restrict__ gt,
    float* __restrict__ msbuf, float* __restrict__ cntbuf, float* __restrict__ s2buf,
    float* __restrict__ cand_val, int* __restrict__ cand_idx) {
    int blk = blockIdx.x;
    int bn = blk / NC, ch = blk % NC;
    int b = bn / N;
    int tid = threadIdx.x;
    int wave = tid >> 6, lane = tid & 63;

    const float* gtrow = gt + (size_t)bn * HW;
    const float* pr = pred + (size_t)b * HW;
    const float* fb = feat + ((size_t)b * V + wave * 8) * HW;  // this wave's v-octet

    float ms[8];
#pragma unroll
    for (int v = 0; v < 8; ++v) ms[v] = 0.f;
    float s2 = 0.f, cnt = 0.f;
    float tv[TOPK]; int ti[TOPK];
#pragma unroll
    for (int j = 0; j < TOPK; ++j) { tv[j] = -INFINITY; ti[j] = 0x7fffffff; }

    int c0 = ch * CHUNK;
#pragma unroll
    for (int it = 0; it < 4; ++it) {
        int p = c0 + it * 256 + lane * 4;
        float4 g4 = *reinterpret_cast<const float4*>(gtrow + p);
#pragma unroll
        for (int vv = 0; vv < 8; ++vv) {
            float4 f = *reinterpret_cast<const float4*>(fb + (size_t)vv * HW + p);
            ms[vv] = fmaf(g4.x, f.x, ms[vv]);
            ms[vv] = fmaf(g4.y, f.y, ms[vv]);
            ms[vv] = fmaf(g4.z, f.z, ms[vv]);
            ms[vv] = fmaf(g4.w, f.w, ms[vv]);
            s2 = fmaf(g4.x * f.x, f.x, s2);
            s2 = fmaf(g4.y * f.y, f.y, s2);
            s2 = fmaf(g4.z * f.z, f.z, s2);
            s2 = fmaf(g4.w * f.w, f.w, s2);
        }
        if (wave == 0) {
            cnt += g4.x + g4.y + g4.z + g4.w;
            float4 pd = *reinterpret_cast<const float4*>(pr + p);
            float c[4] = { pd.x * g4.x, pd.y * g4.y, pd.z * g4.z, pd.w * g4.w };
#pragma unroll
            for (int j = 0; j < 4; ++j) {
                float cv2 = c[j]; int ci2 = p + j;
                if (better(cv2, ci2, tv[TOPK - 1], ti[TOPK - 1])) {
                    tv[TOPK - 1] = cv2; ti[TOPK - 1] = ci2;
#pragma unroll
                    for (int k = TOPK - 2; k >= 0; --k) {
                        if (better(tv[k + 1], ti[k + 1], tv[k], ti[k])) {
                            float fv = tv[k]; int fi = ti[k];
                            tv[k] = tv[k + 1]; ti[k] = ti[k + 1];
                            tv[k + 1] = fv; ti[k + 1] = fi;
                        }
                    }
                }
            }
        }
    }

    // wave-level reduction (each wave owns distinct v-octet -> no cross-wave needed)
#pragma unroll
    for (int off = 32; off > 0; off >>= 1) {
        s2 += __shfl_down(s2, off);
#pragma unroll
        for (int v = 0; v < 8; ++v) ms[v] += __shfl_down(ms[v], off);
    }
    if (wave == 0) {
#pragma unroll
        for (int off = 32; off > 0; off >>= 1) cnt += __shfl_down(cnt, off);
    }
    if (lane == 0) {
#pragma unroll
        for (int v = 0; v < 8; ++v) atomicAdd(msbuf + bn * V + wave * 8 + v, ms[v]);
        atomicAdd(s2buf + bn, s2);
        if (wave == 0) atomicAdd(cntbuf + bn, cnt);
    }

    // wave0: 7 rounds of wave argmax over per-lane sorted candidate lists
    if (wave == 0) {
        int cbase = (bn * NC + ch) * TOPK;
#pragma unroll
        for (int round = 0; round < TOPK; ++round) {
            float bv = tv[0]; int bi = ti[0];
#pragma unroll
            for (int off = 32; off > 0; off >>= 1) {
                float ov = __shfl_down(bv, off);
                int oi = __shfl_down(bi, off);
                if (better(ov, oi, bv, bi)) { bv = ov; bi = oi; }
            }
            float wv = __shfl(bv, 0);
            int wi = __shfl(bi, 0);
            if (ti[0] == wi) {  // pixel idx unique -> exactly one lane pops
#pragma unroll
                for (int k = 0; k < TOPK - 1; ++k) { tv[k] = tv[k + 1]; ti[k] = ti[k + 1]; }
                tv[TOPK - 1] = -INFINITY; ti[TOPK - 1] = 0x7fffffff;
            }
            if (lane == 0) { cand_val[cbase + round] = wv; cand_idx[cbase + round] = wi; }
        }
    }
}

// ---------------- kernel B: finalize stats, merge candidates ----------------
__global__ __launch_bounds__(64) void kfinal(
    const float* __restrict__ msbuf, const float* __restrict__ cntbuf,
    const float* __restrict__ s2buf, const int* __restrict__ valid,
    const float* __restrict__ cand_val, const int* __restrict__ cand_idx,
    float* __restrict__ mean_emb, int* __restrict__ topidx, float* __restrict__ out) {
    int bn = blockIdx.x;   // 64 blocks, 64 threads
    int lane = threadIdx.x;

    // mean_emb + embedding l2 (collapsed: S2/pix - |mu|^2), lanes 0..31 handle v
    float cnt = cntbuf[bn];
    float pix = fmaxf(cnt, 1.0f);
    float musq = 0.f;
    if (lane < V) {
        float mu = msbuf[bn * V + lane] / pix;
        mean_emb[bn * V + lane] = mu;
        musq = mu * mu;
    }
#pragma unroll
    for (int off = 32; off > 0; off >>= 1) musq += __shfl_down(musq, off);
    if (lane == 0) {
        float emb = s2buf[bn] / pix - musq;
        atomicAdd(out + 2, emb * (float)valid[bn]);
    }

    // merge NC*7=175 candidates -> top 7. lane holds up to 3 in registers.
    int cbase = bn * NC * TOPK;
    float cv0 = -INFINITY, cv1 = -INFINITY, cv2 = -INFINITY;
    int ci0 = 0x7fffffff, ci1 = 0x7fffffff, ci2 = 0x7fffffff;
    {
        int j0 = lane, j1 = lane + 64, j2 = lane + 128;
        if (j0 < NC * TOPK) { cv0 = cand_val[cbase + j0]; ci0 = cand_idx[cbase + j0]; }
        if (j1 < NC * TOPK) { cv1 = cand_val[cbase + j1]; ci1 = cand_idx[cbase + j1]; }
        if (j2 < NC * TOPK) { cv2 = cand_val[cbase + j2]; ci2 = cand_idx[cbase + j2]; }
    }
#pragma unroll
    for (int round = 0; round < TOPK; ++round) {
        float bv = cv0; int bi = ci0;
        if (better(cv1, ci1, bv, bi)) { bv = cv1; bi = ci1; }
        if (better(cv2, ci2, bv, bi)) { bv = cv2; bi = ci2; }
#pragma unroll
        for (int off = 32; off > 0; off >>= 1) {
            float ov = __shfl_down(bv, off);
            int oi = __shfl_down(bi, off);
            if (better(ov, oi, bv, bi)) { bv = ov; bi = oi; }
        }
        int wi = __shfl(bi, 0);
        if (ci0 == wi) { cv0 = -INFINITY; ci0 = 0x7fffffff; }
        if (ci1 == wi) { cv1 = -INFINITY; ci1 = 0x7fffffff; }
        if (ci2 == wi) { cv2 = -INFINITY; ci2 = 0x7fffffff; }
        if (lane == 0) topidx[bn * TOPK + round] = wi;
    }
}

// ---------------- kernel C: 8-row sigmoid-GEMM dice partial sums ----------------
__global__ __launch_bounds__(256) void kdice(
    const float* __restrict__ feat, const float* __restrict__ gt,
    const float* __restrict__ mean_emb, const int* __restrict__ topidx,
    float* __restrict__ sums) {
    int blk = blockIdx.x;
    int bn = blk / NC, ch = blk % NC;
    int b = bn / N;
    int tid = threadIdx.x;

    const float* fb = feat + (size_t)b * V * HW;

    __shared__ float e[8][V];
    {
        int r = tid >> 5, v = tid & 31;
        float val;
        if (r == 0) val = mean_emb[bn * V + v];
        else {
            int ix = topidx[bn * TOPK + r - 1];
            val = fb[(size_t)v * HW + ix];
        }
        e[r][v] = val;
    }
    __syncthreads();

    int p = ch * CHUNK + tid * 4;
    const float4 g4 = *reinterpret_cast<const float4*>(gt + (size_t)bn * HW + p);
    float g[4] = { g4.x, g4.y, g4.z, g4.w };

    float m[4][8];
#pragma unroll
    for (int j = 0; j < 4; ++j)
#pragma unroll
        for (int r = 0; r < 8; ++r) m[j][r] = 0.f;

#pragma unroll
    for (int q = 0; q < 8; ++q) {
        float fv[4][4];
#pragma unroll
        for (int vv = 0; vv < 4; ++vv) {
            float4 f = *reinterpret_cast<const float4*>(fb + (size_t)(q * 4 + vv) * HW + p);
            fv[vv][0] = f.x; fv[vv][1] = f.y; fv[vv][2] = f.z; fv[vv][3] = f.w;
        }
        float ev[8][4];
#pragma unroll
        for (int r = 0; r < 8; ++r) {
            float4 t = *reinterpret_cast<const float4*>(&e[r][q * 4]);
            ev[r][0] = t.x; ev[r][1] = t.y; ev[r][2] = t.z; ev[r][3] = t.w;
        }
#pragma unroll
        for (int vv = 0; vv < 4; ++vv)
#pragma unroll
            for (int j = 0; j < 4; ++j)
#pragma unroll
                for (int r = 0; r < 8; ++r)
                    m[j][r] = fmaf(ev[r][vv], fv[vv][j], m[j][r]);
    }

    float p2[8], tp[8];
#pragma unroll
    for (int r = 0; r < 8; ++r) { p2[r] = 0.f; tp[r] = 0.f; }
#pragma unroll
    for (int j = 0; j < 4; ++j) {
#pragma unroll
        for (int r = 0; r < 8; ++r) {
            float s = 1.f / (1.f + __expf(-m[j][r]));
            p2[r] = fmaf(s, s, p2[r]);
            tp[r] = fmaf(g[j], s, tp[r]);
        }
    }

    int lane = tid & 63, wave = tid >> 6;
#pragma unroll
    for (int off = 32; off > 0; off >>= 1) {
#pragma unroll
        for (int r = 0; r < 8; ++r) {
            p2[r] += __shfl_down(p2[r], off);
            tp[r] += __shfl_down(tp[r], off);
        }
    }
    __shared__ float red[4][16];
    if (lane == 0) {
#pragma unroll
        for (int r = 0; r < 8; ++r) { red[wave][r * 2] = p2[r]; red[wave][r * 2 + 1] = tp[r]; }
    }
    __syncthreads();
    if (tid < 16) {
        float s = red[0][tid] + red[1][tid] + red[2][tid] + red[3][tid];
        atomicAdd(sums + bn * 16 + tid, s);
    }
}

// ---------------- kernel D: fold dice sums into losses ----------------
__global__ void kfold(const float* __restrict__ sums, const float* __restrict__ cntbuf,
                      const int* __restrict__ valid, float* __restrict__ out) {
    int bn = threadIdx.x;   // 64 threads
    float vw = (float)valid[bn];
    float cnt = cntbuf[bn];
    float mloss = 0.f, iloss = 0.f;
#pragma unroll
    for (int r = 0; r < 8; ++r) {
        float p2 = sums[bn * 16 + r * 2];
        float tp = sums[bn * 16 + r * 2 + 1];
        float denom = fmaxf(p2 + cnt, 1e-8f);
        float dice = 1.f - 2.f * tp / denom;
        if (r == 0) mloss = dice * vw;
        else iloss += dice * vw;
    }
    atomicAdd(out + 0, mloss);
    atomicAdd(out + 1, iloss);
}

extern "C" void kernel_launch(void* const* d_in, const int* in_sizes, int n_in,
                              void* d_out, int out_size, void* d_ws, size_t ws_size,
                              hipStream_t stream) {
    const float* pred = (const float*)d_in[0];
    const float* feat = (const float*)d_in[1];
    const float* gtin = (const float*)d_in[2];
    const int* valid  = (const int*)d_in[3];
    float* out = (float*)d_out;

    char* ws = (char*)d_ws;
    // zeroed region: [msbuf 8192 | cntbuf 256 | s2buf 256 | sums 4096] = 12800 B
    float* msbuf    = (float*)(ws);
    float* cntbuf   = (float*)(ws + 8192);
    float* s2buf    = (float*)(ws + 8448);
    float* sums     = (float*)(ws + 8704);
    float* mean_emb = (float*)(ws + 12800);
    float* cand_val = (float*)(ws + 20992);   // 64*25*7 floats = 44800 B
    int*   cand_idx = (int*)  (ws + 65792);   // 44800 B
    int*   topidx   = (int*)  (ws + 110592);  // 1792 B

    hipMemsetAsync(out, 0, 3 * sizeof(float), stream);
    hipMemsetAsync(ws, 0, 12800, stream);

    kstats<<<B * N * NC, 256, 0, stream>>>(pred, feat, gtin, msbuf, cntbuf, s2buf,
                                           cand_val, cand_idx);
    kfinal<<<B * N, 64, 0, stream>>>(msbuf, cntbuf, s2buf, valid,
                                     cand_val, cand_idx, mean_emb, topidx, out);
    kdice<<<B * N * NC, 256, 0, stream>>>(feat, gtin, mean_emb, topidx, sums);
    kfold<<<1, 64, 0, stream>>>(sums, cntbuf, valid, out);
}